// Round 4
// baseline (885.111 us; speedup 1.0000x reference)
//
#include <hip/hip_runtime.h>
#include <stdint.h>

#define NNODES 50000
#define NEDGES 800000
#define H 128
#define BN_EPS 1e-5f

typedef short short8 __attribute__((ext_vector_type(8)));
typedef float f32x4 __attribute__((ext_vector_type(4)));

__device__ __forceinline__ float bf2f(unsigned short u) {
    unsigned int v = ((unsigned int)u) << 16;
    return __uint_as_float(v);
}
__device__ __forceinline__ unsigned short f2bf(float f) {
    unsigned int x = __float_as_uint(f);
    return (unsigned short)((x + 0x7FFFu + ((x >> 16) & 1u)) >> 16);
}
__device__ __forceinline__ short8 s8z() { short8 z = {0,0,0,0,0,0,0,0}; return z; }

// ================= common MFMA tile core =================
template<int KB>
__device__ __forceinline__ void gemm_tile(const short* __restrict__ sA, const int SK,
                                          const unsigned short* __restrict__ WT, const int RK,
                                          const int n0, f32x4 acc[4][4], const int lane) {
    const int mr = lane & 15, quad = lane >> 4;
    const short* W = (const short*)WT;
    #pragma unroll
    for (int kb = 0; kb < KB; ++kb) {
        short8 a[4];
        #pragma unroll
        for (int mt = 0; mt < 4; ++mt)
            a[mt] = *(const short8*)&sA[(mt*16 + mr)*SK + kb*32 + quad*8];
        #pragma unroll
        for (int nt = 0; nt < 4; ++nt) {
            short8 b = *(const short8*)&W[(size_t)(n0 + nt*16 + mr)*RK + kb*32 + quad*8];
            #pragma unroll
            for (int mt = 0; mt < 4; ++mt)
                acc[mt][nt] = __builtin_amdgcn_mfma_f32_16x16x32_bf16(a[mt], b, acc[mt][nt], 0, 0, 0);
        }
    }
}

// ---- fold We2@Wm -> W2m (f32), b2m = be2@Wm + bm ----
__global__ void k_fold(const float* __restrict__ We2, const float* __restrict__ be2,
                       const float* __restrict__ Wm, const float* __restrict__ bm,
                       float* __restrict__ W2m, float* __restrict__ b2m) {
    int j = threadIdx.x;
    int i = blockIdx.x;
    if (i < H) {
        float acc = 0.f;
        for (int k = 0; k < H; ++k) acc = fmaf(We2[i*H + k], Wm[k*H + j], acc);
        W2m[i*H + j] = acc;
    } else {
        float acc = bm[j];
        for (int k = 0; k < H; ++k) acc = fmaf(be2[k], Wm[k*H + j], acc);
        b2m[j] = acc;
    }
}

// ---- transposed bf16 weight copies for MFMA B-frags ----
__global__ void k_prep2(const float* __restrict__ We1, const float* __restrict__ Wn1,
                        const float* __restrict__ Wn2, const float* __restrict__ W2m,
                        unsigned short* __restrict__ WabT, unsigned short* __restrict__ Wn1T,
                        unsigned short* __restrict__ Wn2T, unsigned short* __restrict__ W2mT) {
    int i = blockIdx.x*256 + threadIdx.x;
    if (i < 16384) {                        // WabT[256][64]
        int n = i >> 6, k = i & 63;
        WabT[n*64 + k] = f2bf(We1[(n < 128 ? k : 64 + k)*H + (n & 127)]);
    } else if (i < 40960) {                 // Wn1T[128][192]
        int j = i - 16384; int n = j / 192, k = j - n*192;
        Wn1T[n*192 + k] = f2bf(Wn1[k*H + n]);
    } else if (i < 57344) {                 // Wn2T[128][128]
        int j = i - 40960; int n = j >> 7, k = j & 127;
        Wn2T[n*H + k] = f2bf(Wn2[k*H + n]);
    } else if (i < 73728) {                 // W2mT[128][128]
        int j = i - 57344; int n = j >> 7, k = j & 127;
        W2mT[n*H + k] = f2bf(W2m[k*H + n]);
    }
}

// ---- CSR build ----
__global__ void k_count(const int* __restrict__ ei, int* __restrict__ cnt) {
    int e = blockIdx.x*256 + threadIdx.x;
    if (e < NEDGES) atomicAdd(&cnt[ei[e]], 1);
}

__global__ void k_scan(const int* __restrict__ cnt, int* __restrict__ offsets,
                       int* __restrict__ cursor) {
    __shared__ int wsum[16];
    __shared__ int carry;
    const int tid = threadIdx.x;
    const int lane = tid & 63, wid = tid >> 6;
    if (tid == 0) carry = 0;
    for (int base = 0; base < NNODES; base += 1024) {
        int i = base + tid;
        int v = (i < NNODES) ? cnt[i] : 0;
        int xv = v;
        #pragma unroll
        for (int off = 1; off < 64; off <<= 1) {
            int y = __shfl_up(xv, off);
            if (lane >= off) xv += y;
        }
        if (lane == 63) wsum[wid] = xv;
        __syncthreads();
        if (tid == 0) {
            int a = carry;
            #pragma unroll
            for (int j = 0; j < 16; ++j) { int t = wsum[j]; wsum[j] = a; a += t; }
            carry = a;
        }
        __syncthreads();
        int excl = wsum[wid] + xv - v;
        if (i < NNODES) { offsets[i] = excl; cursor[i] = excl; }
        __syncthreads();
    }
    if (tid == 0) offsets[NNODES] = carry;
}

__global__ void k_scatter(const int* __restrict__ ei, int* __restrict__ cursor,
                          int* __restrict__ elist) {
    int e = blockIdx.x*256 + threadIdx.x;
    if (e < NEDGES) {
        int p = atomicAdd(&cursor[ei[e]], 1);
        elist[p] = e;
    }
}

// ---- T = x @ [Wa | Wb]  (bf16 out, [50000][256]) ----
__launch_bounds__(256)
__global__ void k_T(const float* __restrict__ x, const unsigned short* __restrict__ WabT,
                    unsigned short* __restrict__ T) {
    __shared__ short sA[128*72];
    const int tid = threadIdx.x;
    const int n0b = blockIdx.x*128;
    {
        const int rowl = tid >> 1, half = (tid & 1)*32;
        const int node = n0b + rowl;
        const bool ok = node < NNODES;
        #pragma unroll
        for (int c = 0; c < 4; ++c) {
            int k0 = half + c*8;
            short8 o = s8z();
            if (ok) {
                float4 a = *(const float4*)&x[node*64 + k0];
                float4 b = *(const float4*)&x[node*64 + k0 + 4];
                o[0]=(short)f2bf(a.x); o[1]=(short)f2bf(a.y); o[2]=(short)f2bf(a.z); o[3]=(short)f2bf(a.w);
                o[4]=(short)f2bf(b.x); o[5]=(short)f2bf(b.y); o[6]=(short)f2bf(b.z); o[7]=(short)f2bf(b.w);
            }
            *(short8*)&sA[rowl*72 + k0] = o;
        }
    }
    __syncthreads();
    const int wave = tid >> 6, lane = tid & 63;
    const int m0 = (wave & 1)*64;
    const int n0 = blockIdx.y*128 + (wave >> 1)*64;
    f32x4 acc[4][4];
    f32x4 z = {0.f, 0.f, 0.f, 0.f};
    #pragma unroll
    for (int mt = 0; mt < 4; ++mt)
        #pragma unroll
        for (int nt = 0; nt < 4; ++nt) acc[mt][nt] = z;
    gemm_tile<2>(sA + m0*72, 72, WabT, 64, n0, acc, lane);
    const int mr = lane & 15, quad = lane >> 4;
    #pragma unroll
    for (int nt = 0; nt < 4; ++nt) {
        int j = n0 + nt*16 + mr;
        #pragma unroll
        for (int mt = 0; mt < 4; ++mt) {
            int nb = n0b + m0 + mt*16 + quad*4;
            #pragma unroll
            for (int r = 0; r < 4; ++r) {
                int node = nb + r;
                if (node < NNODES) T[(size_t)node*256 + j] = f2bf(acc[mt][nt][r]);
            }
        }
    }
}

// ---- pass A: BN stats of h1 WITHOUT storing h1 ----
// 16 lanes/edge, Wc regs, 40000 slots x 20 edges.
__launch_bounds__(256)
__global__ void k_stats_edges(const unsigned short* __restrict__ T, const int* __restrict__ ei,
                              const float* __restrict__ ea, const float* __restrict__ We1,
                              const float* __restrict__ be1,
                              float* __restrict__ gS, float* __restrict__ gSS) {
    __shared__ float sS[H], sSS[H];
    const int tid = threadIdx.x;
    if (tid < H) { sS[tid] = 0.f; sSS[tid] = 0.f; }
    const int li = tid & 15;
    const int slot = (blockIdx.x*256 + tid) >> 4;      // 0..39999
    float4 wcA[16], wcB[16];
    #pragma unroll
    for (int k = 0; k < 16; ++k) {
        wcA[k] = *(const float4*)&We1[(128 + k)*H + li*8];
        wcB[k] = *(const float4*)&We1[(128 + k)*H + li*8 + 4];
    }
    float be[8];
    #pragma unroll
    for (int i = 0; i < 8; ++i) be[i] = be1[li*8 + i];
    float s[8], ss[8];
    #pragma unroll
    for (int i = 0; i < 8; ++i) { s[i] = 0.f; ss[i] = 0.f; }
    const float4* ea4 = (const float4*)ea;
    for (int it = 0; it < 20; ++it) {
        int e = slot + it*40000;
        int row = ei[e], col = ei[NEDGES + e];
        short8 t1 = *(const short8*)&T[(size_t)row*256 + li*8];
        short8 t2 = *(const short8*)&T[(size_t)col*256 + 128 + li*8];
        float4 ev[4];
        #pragma unroll
        for (int q = 0; q < 4; ++q) ev[q] = ea4[e*4 + q];
        float v[8];
        #pragma unroll
        for (int i = 0; i < 8; ++i)
            v[i] = bf2f((unsigned short)t1[i]) + bf2f((unsigned short)t2[i]) + be[i];
        #pragma unroll
        for (int q = 0; q < 4; ++q) {
            float aa[4] = {ev[q].x, ev[q].y, ev[q].z, ev[q].w};
            #pragma unroll
            for (int kk = 0; kk < 4; ++kk) {
                int k = q*4 + kk;
                float a = aa[kk];
                v[0] = fmaf(a, wcA[k].x, v[0]); v[1] = fmaf(a, wcA[k].y, v[1]);
                v[2] = fmaf(a, wcA[k].z, v[2]); v[3] = fmaf(a, wcA[k].w, v[3]);
                v[4] = fmaf(a, wcB[k].x, v[4]); v[5] = fmaf(a, wcB[k].y, v[5]);
                v[6] = fmaf(a, wcB[k].z, v[6]); v[7] = fmaf(a, wcB[k].w, v[7]);
            }
        }
        #pragma unroll
        for (int i = 0; i < 8; ++i) { s[i] += v[i]; ss[i] += v[i]*v[i]; }
    }
    __syncthreads();
    #pragma unroll
    for (int i = 0; i < 8; ++i) {
        atomicAdd(&sS[li*8 + i], s[i]);
        atomicAdd(&sSS[li*8 + i], ss[i]);
    }
    __syncthreads();
    if (tid < H) { atomicAdd(&gS[tid], sS[tid]); atomicAdd(&gSS[tid], sSS[tid]); }
}

// ---- BN stats -> scale/shift ----
__global__ void k_stats(const float* __restrict__ S, const float* __restrict__ SS,
                        const float* __restrict__ g, const float* __restrict__ b,
                        float invCount, float* __restrict__ scale, float* __restrict__ shift) {
    int j = threadIdx.x;
    float mu = S[j]*invCount;
    float var = SS[j]*invCount - mu*mu;
    float sc = rsqrtf(var + BN_EPS)*g[j];
    scale[j] = sc;
    shift[j] = b[j] - mu*sc;
}

// ---- pass B: fused recompute-h1 -> BN+ReLU -> GEMM(W2m) -> ReLU -> segment-reduce -> agg ----
// One block = 128 CSR-sorted edge positions.
__launch_bounds__(256)
__global__ void k_fused(const unsigned short* __restrict__ T, const int* __restrict__ ei,
                        const int* __restrict__ elist, const int* __restrict__ offsets,
                        const float* __restrict__ ea, const float* __restrict__ We1,
                        const float* __restrict__ be1, const float* __restrict__ scale,
                        const float* __restrict__ shift, const unsigned short* __restrict__ W2mT,
                        const float* __restrict__ b2m, float* __restrict__ agg) {
    __shared__ short sA[128*136];          // A-tile (h1 bf16), later reused as msg tile
    __shared__ float sWc[16*128];          // We1 rows 128..143
    __shared__ int rows[128];
    const int tid = threadIdx.x;
    const int p0 = blockIdx.x*128;
    for (int i = tid; i < 2048; i += 256) sWc[i] = We1[16384 + i];
    const int lp = tid >> 1, half = tid & 1;
    const int e = elist[p0 + lp];
    const int row = ei[e], col = ei[NEDGES + e];
    if (half == 0) rows[lp] = row;
    const float4* ea4 = (const float4*)ea;
    float4 ev[4];
    #pragma unroll
    for (int q = 0; q < 4; ++q) ev[q] = ea4[e*4 + q];
    __syncthreads();
    const int j0 = half*64;
    #pragma unroll
    for (int c = 0; c < 8; ++c) {
        const int jj = j0 + c*8;
        short8 t1 = *(const short8*)&T[(size_t)row*256 + jj];
        short8 t2 = *(const short8*)&T[(size_t)col*256 + 128 + jj];
        float v[8];
        #pragma unroll
        for (int i = 0; i < 8; ++i)
            v[i] = bf2f((unsigned short)t1[i]) + bf2f((unsigned short)t2[i]) + be1[jj + i];
        #pragma unroll
        for (int q = 0; q < 4; ++q) {
            float aa[4] = {ev[q].x, ev[q].y, ev[q].z, ev[q].w};
            #pragma unroll
            for (int kk = 0; kk < 4; ++kk) {
                int k = q*4 + kk;
                float a = aa[kk];
                float4 w0 = *(const float4*)&sWc[k*128 + jj];
                float4 w1 = *(const float4*)&sWc[k*128 + jj + 4];
                v[0] = fmaf(a, w0.x, v[0]); v[1] = fmaf(a, w0.y, v[1]);
                v[2] = fmaf(a, w0.z, v[2]); v[3] = fmaf(a, w0.w, v[3]);
                v[4] = fmaf(a, w1.x, v[4]); v[5] = fmaf(a, w1.y, v[5]);
                v[6] = fmaf(a, w1.z, v[6]); v[7] = fmaf(a, w1.w, v[7]);
            }
        }
        short8 o;
        #pragma unroll
        for (int i = 0; i < 8; ++i)
            o[i] = (short)f2bf(fmaxf(fmaf(v[i], scale[jj + i], shift[jj + i]), 0.f));
        *(short8*)&sA[lp*136 + jj] = o;
    }
    __syncthreads();
    const int wave = tid >> 6, lane = tid & 63;
    const int m0 = (wave & 1)*64, n0 = (wave >> 1)*64;
    f32x4 acc[4][4];
    f32x4 z = {0.f, 0.f, 0.f, 0.f};
    #pragma unroll
    for (int mt = 0; mt < 4; ++mt)
        #pragma unroll
        for (int nt = 0; nt < 4; ++nt) acc[mt][nt] = z;
    gemm_tile<4>(sA + m0*136, 136, W2mT, 128, n0, acc, lane);
    __syncthreads();   // all A-tile reads complete; safe to overwrite sA with msg
    const int mr = lane & 15, quad = lane >> 4;
    #pragma unroll
    for (int nt = 0; nt < 4; ++nt) {
        int j = n0 + nt*16 + mr;
        float bias = b2m[j];
        #pragma unroll
        for (int mt = 0; mt < 4; ++mt) {
            int m = m0 + mt*16 + quad*4;
            #pragma unroll
            for (int r = 0; r < 4; ++r)
                sA[(m + r)*136 + j] = (short)f2bf(fmaxf(acc[mt][nt][r] + bias, 0.f));
        }
    }
    __syncthreads();
    // segment reduce by row (rows[] is non-decreasing: elist is CSR-sorted)
    if (tid < 128) {
        const int jf = tid;
        int p = 0;
        while (p < 128) {
            int r = rows[p];
            int q = p + 1;
            while (q < 128 && rows[q] == r) ++q;
            float sum = 0.f;
            for (int i = p; i < q; ++i) sum += bf2f((unsigned short)sA[i*136 + jf]);
            bool full = (p0 + p == offsets[r]) && (p0 + q == offsets[r + 1]);
            float* dst = &agg[(size_t)r*H + jf];
            if (full) *dst = sum;
            else atomicAdd(dst, sum);
            p = q;
        }
    }
}

// ---- h2 = [x, agg] @ Wn1 + bn1 (f32 store) ; BN stats ----
__launch_bounds__(256)
__global__ void k_node1(const float* __restrict__ x, const float* __restrict__ agg,
                        const unsigned short* __restrict__ Wn1T, const float* __restrict__ bn1,
                        float* __restrict__ h2, float* __restrict__ gS, float* __restrict__ gSS) {
    __shared__ short sA[128*200];
    __shared__ float sS[H], sSS[H];
    const int tid = threadIdx.x;
    if (tid < H) { sS[tid] = 0.f; sSS[tid] = 0.f; }
    const int n0b = blockIdx.x*128;
    {
        const int rowl = tid >> 1, half = (tid & 1)*96;
        const int node = n0b + rowl;
        const bool ok = node < NNODES;
        #pragma unroll
        for (int c = 0; c < 12; ++c) {
            int k0 = half + c*8;
            short8 o = s8z();
            if (ok) {
                float4 a, b;
                if (k0 < 64) {
                    a = *(const float4*)&x[node*64 + k0];
                    b = *(const float4*)&x[node*64 + k0 + 4];
                } else {
                    a = *(const float4*)&agg[(size_t)node*H + (k0 - 64)];
                    b = *(const float4*)&agg[(size_t)node*H + (k0 - 64) + 4];
                }
                o[0]=(short)f2bf(a.x); o[1]=(short)f2bf(a.y); o[2]=(short)f2bf(a.z); o[3]=(short)f2bf(a.w);
                o[4]=(short)f2bf(b.x); o[5]=(short)f2bf(b.y); o[6]=(short)f2bf(b.z); o[7]=(short)f2bf(b.w);
            }
            *(short8*)&sA[rowl*200 + k0] = o;
        }
    }
    __syncthreads();
    const int wave = tid >> 6, lane = tid & 63;
    const int m0 = (wave & 1)*64, n0 = (wave >> 1)*64;
    f32x4 acc[4][4];
    f32x4 z = {0.f, 0.f, 0.f, 0.f};
    #pragma unroll
    for (int mt = 0; mt < 4; ++mt)
        #pragma unroll
        for (int nt = 0; nt < 4; ++nt) acc[mt][nt] = z;
    gemm_tile<6>(sA + m0*200, 200, Wn1T, 192, n0, acc, lane);
    const int mr = lane & 15, quad = lane >> 4;
    #pragma unroll
    for (int nt = 0; nt < 4; ++nt) {
        int j = n0 + nt*16 + mr;
        float bias = bn1[j];
        float s = 0.f, ssum = 0.f;
        #pragma unroll
        for (int mt = 0; mt < 4; ++mt) {
            int nb = n0b + m0 + mt*16 + quad*4;
            #pragma unroll
            for (int r = 0; r < 4; ++r) {
                int node = nb + r;
                if (node < NNODES) {
                    float v = acc[mt][nt][r] + bias;
                    h2[(size_t)node*H + j] = v;
                    s += v; ssum += v*v;
                }
            }
        }
        atomicAdd(&sS[j], s);
        atomicAdd(&sSS[j], ssum);
    }
    __syncthreads();
    if (tid < H) { atomicAdd(&gS[tid], sS[tid]); atomicAdd(&gSS[tid], sSS[tid]); }
}

// ---- out = relu(bn(h2)) @ Wn2 + bn2 (f32) ----
__launch_bounds__(256)
__global__ void k_node2(const float* __restrict__ h2, const float* __restrict__ scale,
                        const float* __restrict__ shift, const unsigned short* __restrict__ Wn2T,
                        const float* __restrict__ bn2, float* __restrict__ out) {
    __shared__ short sA[128*136];
    const int tid = threadIdx.x;
    const int n0b = blockIdx.x*128;
    {
        const int rowl = tid >> 1, half = (tid & 1)*64;
        const int node = n0b + rowl;
        const bool ok = node < NNODES;
        #pragma unroll
        for (int c = 0; c < 8; ++c) {
            int k0 = half + c*8;
            short8 o = s8z();
            if (ok) {
                float4 a = *(const float4*)&h2[(size_t)node*H + k0];
                float4 b = *(const float4*)&h2[(size_t)node*H + k0 + 4];
                float4 sc0 = *(const float4*)&scale[k0], sc1 = *(const float4*)&scale[k0 + 4];
                float4 sh0 = *(const float4*)&shift[k0], sh1 = *(const float4*)&shift[k0 + 4];
                o[0] = (short)f2bf(fmaxf(fmaf(a.x, sc0.x, sh0.x), 0.f));
                o[1] = (short)f2bf(fmaxf(fmaf(a.y, sc0.y, sh0.y), 0.f));
                o[2] = (short)f2bf(fmaxf(fmaf(a.z, sc0.z, sh0.z), 0.f));
                o[3] = (short)f2bf(fmaxf(fmaf(a.w, sc0.w, sh0.w), 0.f));
                o[4] = (short)f2bf(fmaxf(fmaf(b.x, sc1.x, sh1.x), 0.f));
                o[5] = (short)f2bf(fmaxf(fmaf(b.y, sc1.y, sh1.y), 0.f));
                o[6] = (short)f2bf(fmaxf(fmaf(b.z, sc1.z, sh1.z), 0.f));
                o[7] = (short)f2bf(fmaxf(fmaf(b.w, sc1.w, sh1.w), 0.f));
            }
            *(short8*)&sA[rowl*136 + k0] = o;
        }
    }
    __syncthreads();
    const int wave = tid >> 6, lane = tid & 63;
    const int m0 = (wave & 1)*64, n0 = (wave >> 1)*64;
    f32x4 acc[4][4];
    f32x4 z = {0.f, 0.f, 0.f, 0.f};
    #pragma unroll
    for (int mt = 0; mt < 4; ++mt)
        #pragma unroll
        for (int nt = 0; nt < 4; ++nt) acc[mt][nt] = z;
    gemm_tile<4>(sA + m0*136, 136, Wn2T, 128, n0, acc, lane);
    const int mr = lane & 15, quad = lane >> 4;
    #pragma unroll
    for (int nt = 0; nt < 4; ++nt) {
        int j = n0 + nt*16 + mr;
        float bias = bn2[j];
        #pragma unroll
        for (int mt = 0; mt < 4; ++mt) {
            int nb = n0b + m0 + mt*16 + quad*4;
            #pragma unroll
            for (int r = 0; r < 4; ++r) {
                int node = nb + r;
                if (node < NNODES) out[(size_t)node*H + j] = acc[mt][nt][r] + bias;
            }
        }
    }
}

extern "C" void kernel_launch(void* const* d_in, const int* in_sizes, int n_in,
                              void* d_out, int out_size, void* d_ws, size_t ws_size,
                              hipStream_t stream) {
    (void)in_sizes; (void)n_in; (void)out_size; (void)ws_size;
    const float* x   = (const float*)d_in[0];
    const int*   ei  = (const int*)d_in[1];
    const float* ea  = (const float*)d_in[2];
    const float* We1 = (const float*)d_in[3];
    const float* be1 = (const float*)d_in[4];
    const float* ge  = (const float*)d_in[5];
    const float* bbe = (const float*)d_in[6];
    const float* We2 = (const float*)d_in[7];
    const float* be2 = (const float*)d_in[8];
    const float* Wm  = (const float*)d_in[9];
    const float* bm  = (const float*)d_in[10];
    const float* Wn1 = (const float*)d_in[11];
    const float* bn1 = (const float*)d_in[12];
    const float* gn  = (const float*)d_in[13];
    const float* bbn = (const float*)d_in[14];
    const float* Wn2 = (const float*)d_in[15];
    const float* bn2 = (const float*)d_in[16];
    float* out = (float*)d_out;

    char* ws = (char*)d_ws;
    // [0, 25.6M)        T bf16 [N][256]
    // [25.6M, 51.2M)    agg f32 [N][128]
    // [51.2M, 76.8M)    h2 f32 [N][128]
    // [76.8M, ~81M)     CSR + stats + weight copies
    unsigned short* Tbuf = (unsigned short*)(ws);
    float* agg = (float*)(ws + 25600000);
    float* h2  = (float*)(ws + 51200000);
    int* cnt     = (int*)(ws + 76800000);
    int* offsets = (int*)(ws + 77000192);
    int* cursor  = (int*)(ws + 77200256);
    int* elist   = (int*)(ws + 77400320);
    float* S1     = (float*)(ws + 80600384);
    float* SS1    = S1 + 128;
    float* S2     = S1 + 256;
    float* SS2    = S1 + 384;
    float* scale1 = S1 + 512;
    float* shift1 = S1 + 640;
    float* scale2 = S1 + 768;
    float* shift2 = S1 + 896;
    float* W2m = (float*)(ws + 80604480);
    float* b2m = (float*)(ws + 80670016);
    unsigned short* WabT = (unsigned short*)(ws + 80670592);
    unsigned short* Wn1T = (unsigned short*)(ws + 80703360);
    unsigned short* Wn2T = (unsigned short*)(ws + 80752512);
    unsigned short* W2mT = (unsigned short*)(ws + 80785280);

    hipMemsetAsync(cnt, 0, NNODES*sizeof(int), stream);
    hipMemsetAsync(S1, 0, 512*sizeof(float), stream);
    hipMemsetAsync(agg, 0, (size_t)NNODES*H*sizeof(float), stream);

    k_fold<<<H + 1, H, 0, stream>>>(We2, be2, Wm, bm, W2m, b2m);
    k_prep2<<<288, 256, 0, stream>>>(We1, Wn1, Wn2, W2m, WabT, Wn1T, Wn2T, W2mT);
    k_count<<<NEDGES/256, 256, 0, stream>>>(ei, cnt);
    k_scan<<<1, 1024, 0, stream>>>(cnt, offsets, cursor);
    k_scatter<<<NEDGES/256, 256, 0, stream>>>(ei, cursor, elist);
    k_T<<<dim3(391, 2), 256, 0, stream>>>(x, WabT, Tbuf);
    k_stats_edges<<<2500, 256, 0, stream>>>(Tbuf, ei, ea, We1, be1, S1, SS1);
    k_stats<<<1, H, 0, stream>>>(S1, SS1, ge, bbe, 1.0f/NEDGES, scale1, shift1);
    k_fused<<<NEDGES/128, 256, 0, stream>>>(Tbuf, ei, elist, offsets, ea, We1, be1,
                                            scale1, shift1, W2mT, b2m, agg);
    k_node1<<<391, 256, 0, stream>>>(x, agg, Wn1T, bn1, h2, S2, SS2);
    k_stats<<<1, H, 0, stream>>>(S2, SS2, gn, bbn, 1.0f/NNODES, scale2, shift2);
    k_node2<<<391, 256, 0, stream>>>(h2, scale2, shift2, Wn2T, bn2, out);
}

// Round 5
// 733.321 us; speedup vs baseline: 1.2070x; 1.2070x over previous
//
#include <hip/hip_runtime.h>
#include <stdint.h>

#define NNODES 50000
#define NEDGES 800000
#define H 128
#define BN_EPS 1e-5f

typedef short short8 __attribute__((ext_vector_type(8)));
typedef float f32x4 __attribute__((ext_vector_type(4)));

__device__ __forceinline__ float bf2f(unsigned short u) {
    unsigned int v = ((unsigned int)u) << 16;
    return __uint_as_float(v);
}
__device__ __forceinline__ unsigned short f2bf(float f) {
    unsigned int x = __float_as_uint(f);
    return (unsigned short)((x + 0x7FFFu + ((x >> 16) & 1u)) >> 16);
}
__device__ __forceinline__ short8 s8z() { short8 z = {0,0,0,0,0,0,0,0}; return z; }

// ================= common MFMA tile core =================
template<int KB>
__device__ __forceinline__ void gemm_tile(const short* __restrict__ sA, const int SK,
                                          const unsigned short* __restrict__ WT, const int RK,
                                          const int n0, f32x4 acc[4][4], const int lane) {
    const int mr = lane & 15, quad = lane >> 4;
    const short* W = (const short*)WT;
    #pragma unroll
    for (int kb = 0; kb < KB; ++kb) {
        short8 a[4];
        #pragma unroll
        for (int mt = 0; mt < 4; ++mt)
            a[mt] = *(const short8*)&sA[(mt*16 + mr)*SK + kb*32 + quad*8];
        #pragma unroll
        for (int nt = 0; nt < 4; ++nt) {
            short8 b = *(const short8*)&W[(size_t)(n0 + nt*16 + mr)*RK + kb*32 + quad*8];
            #pragma unroll
            for (int mt = 0; mt < 4; ++mt)
                acc[mt][nt] = __builtin_amdgcn_mfma_f32_16x16x32_bf16(a[mt], b, acc[mt][nt], 0, 0, 0);
        }
    }
}

// ---- fold We2@Wm -> W2m (f32), b2m = be2@Wm + bm ----
__global__ void k_fold(const float* __restrict__ We2, const float* __restrict__ be2,
                       const float* __restrict__ Wm, const float* __restrict__ bm,
                       float* __restrict__ W2m, float* __restrict__ b2m) {
    int j = threadIdx.x;
    int i = blockIdx.x;
    if (i < H) {
        float acc = 0.f;
        for (int k = 0; k < H; ++k) acc = fmaf(We2[i*H + k], Wm[k*H + j], acc);
        W2m[i*H + j] = acc;
    } else {
        float acc = bm[j];
        for (int k = 0; k < H; ++k) acc = fmaf(be2[k], Wm[k*H + j], acc);
        b2m[j] = acc;
    }
}

// ---- transposed bf16 weight copies for MFMA B-frags ----
__global__ void k_prep2(const float* __restrict__ We1, const float* __restrict__ Wn1,
                        const float* __restrict__ Wn2, const float* __restrict__ W2m,
                        unsigned short* __restrict__ WabT, unsigned short* __restrict__ Wn1T,
                        unsigned short* __restrict__ Wn2T, unsigned short* __restrict__ W2mT,
                        unsigned short* __restrict__ WcT) {
    int i = blockIdx.x*256 + threadIdx.x;
    if (i < 16384) {                        // WabT[256][64]
        int n = i >> 6, k = i & 63;
        WabT[n*64 + k] = f2bf(We1[(n < 128 ? k : 64 + k)*H + (n & 127)]);
    } else if (i < 40960) {                 // Wn1T[128][192]
        int j = i - 16384; int n = j / 192, k = j - n*192;
        Wn1T[n*192 + k] = f2bf(Wn1[k*H + n]);
    } else if (i < 57344) {                 // Wn2T[128][128]
        int j = i - 40960; int n = j >> 7, k = j & 127;
        Wn2T[n*H + k] = f2bf(Wn2[k*H + n]);
    } else if (i < 73728) {                 // W2mT[128][128]
        int j = i - 57344; int n = j >> 7, k = j & 127;
        W2mT[n*H + k] = f2bf(W2m[k*H + n]);
    } else if (i < 77824) {                 // WcT[128][32], k>=16 zero (K padded for MFMA)
        int j = i - 73728; int n = j >> 5, k = j & 31;
        WcT[n*32 + k] = (k < 16) ? f2bf(We1[(128 + k)*H + n]) : (unsigned short)0;
    }
}

// ---- CSR build ----
__global__ void k_count(const int* __restrict__ ei, int* __restrict__ cnt) {
    int e = blockIdx.x*256 + threadIdx.x;
    if (e < NEDGES) atomicAdd(&cnt[ei[e]], 1);
}

__global__ void k_scan(const int* __restrict__ cnt, int* __restrict__ offsets,
                       int* __restrict__ cursor) {
    __shared__ int wsum[16];
    __shared__ int carry;
    const int tid = threadIdx.x;
    const int lane = tid & 63, wid = tid >> 6;
    if (tid == 0) carry = 0;
    for (int base = 0; base < NNODES; base += 1024) {
        int i = base + tid;
        int v = (i < NNODES) ? cnt[i] : 0;
        int xv = v;
        #pragma unroll
        for (int off = 1; off < 64; off <<= 1) {
            int y = __shfl_up(xv, off);
            if (lane >= off) xv += y;
        }
        if (lane == 63) wsum[wid] = xv;
        __syncthreads();
        if (tid == 0) {
            int a = carry;
            #pragma unroll
            for (int j = 0; j < 16; ++j) { int t = wsum[j]; wsum[j] = a; a += t; }
            carry = a;
        }
        __syncthreads();
        int excl = wsum[wid] + xv - v;
        if (i < NNODES) { offsets[i] = excl; cursor[i] = excl; }
        __syncthreads();
    }
    if (tid == 0) offsets[NNODES] = carry;
}

__global__ void k_scatter(const int* __restrict__ ei, int* __restrict__ cursor,
                          int* __restrict__ elist) {
    int e = blockIdx.x*256 + threadIdx.x;
    if (e < NEDGES) {
        int p = atomicAdd(&cursor[ei[e]], 1);
        elist[p] = e;
    }
}

// ---- T = x @ [Wa | Wb]  (bf16 out, [50000][256]) ----
__launch_bounds__(256)
__global__ void k_T(const float* __restrict__ x, const unsigned short* __restrict__ WabT,
                    unsigned short* __restrict__ T) {
    __shared__ short sA[128*72];
    const int tid = threadIdx.x;
    const int n0b = blockIdx.x*128;
    {
        const int rowl = tid >> 1, half = (tid & 1)*32;
        const int node = n0b + rowl;
        const bool ok = node < NNODES;
        #pragma unroll
        for (int c = 0; c < 4; ++c) {
            int k0 = half + c*8;
            short8 o = s8z();
            if (ok) {
                float4 a = *(const float4*)&x[node*64 + k0];
                float4 b = *(const float4*)&x[node*64 + k0 + 4];
                o[0]=(short)f2bf(a.x); o[1]=(short)f2bf(a.y); o[2]=(short)f2bf(a.z); o[3]=(short)f2bf(a.w);
                o[4]=(short)f2bf(b.x); o[5]=(short)f2bf(b.y); o[6]=(short)f2bf(b.z); o[7]=(short)f2bf(b.w);
            }
            *(short8*)&sA[rowl*72 + k0] = o;
        }
    }
    __syncthreads();
    const int wave = tid >> 6, lane = tid & 63;
    const int m0 = (wave & 1)*64;
    const int n0 = blockIdx.y*128 + (wave >> 1)*64;
    f32x4 acc[4][4];
    f32x4 z = {0.f, 0.f, 0.f, 0.f};
    #pragma unroll
    for (int mt = 0; mt < 4; ++mt)
        #pragma unroll
        for (int nt = 0; nt < 4; ++nt) acc[mt][nt] = z;
    gemm_tile<2>(sA + m0*72, 72, WabT, 64, n0, acc, lane);
    const int mr = lane & 15, quad = lane >> 4;
    #pragma unroll
    for (int nt = 0; nt < 4; ++nt) {
        int j = n0 + nt*16 + mr;
        #pragma unroll
        for (int mt = 0; mt < 4; ++mt) {
            int nb = n0b + m0 + mt*16 + quad*4;
            #pragma unroll
            for (int r = 0; r < 4; ++r) {
                int node = nb + r;
                if (node < NNODES) T[(size_t)node*256 + j] = f2bf(acc[mt][nt][r]);
            }
        }
    }
}

// ---- h1[p] (sorted order) = T1[row] + T2[col] + ea@Wc + be1 ; bf16 store ; BN stats ----
// One block = 128 CSR-sorted edge positions; ea@Wc via MFMA (K=16 zero-padded to 32).
__launch_bounds__(256)
__global__ void k_gather2(const unsigned short* __restrict__ T, const int* __restrict__ ei,
                          const int* __restrict__ elist, const float* __restrict__ ea,
                          const unsigned short* __restrict__ WcT, const float* __restrict__ be1,
                          unsigned short* __restrict__ hb,
                          float* __restrict__ gS, float* __restrict__ gSS) {
    __shared__ short sEa[128*40];      // ea bf16, K=32 (upper 16 zero), pad to 40
    __shared__ short sT[128*136];      // bf16(T1+T2)
    __shared__ float sS[H], sSS[H];
    const int tid = threadIdx.x;
    if (tid < H) { sS[tid] = 0.f; sSS[tid] = 0.f; }
    const int p0 = blockIdx.x*128;
    const int lp = tid >> 1, half = tid & 1;
    const int e = elist[p0 + lp];
    const int row = ei[e], col = ei[NEDGES + e];
    {
        const float4* ea4 = (const float4*)ea;
        float4 a = ea4[e*4 + half*2];
        float4 b = ea4[e*4 + half*2 + 1];
        short8 o;
        o[0]=(short)f2bf(a.x); o[1]=(short)f2bf(a.y); o[2]=(short)f2bf(a.z); o[3]=(short)f2bf(a.w);
        o[4]=(short)f2bf(b.x); o[5]=(short)f2bf(b.y); o[6]=(short)f2bf(b.z); o[7]=(short)f2bf(b.w);
        *(short8*)&sEa[lp*40 + half*8] = o;
        *(short8*)&sEa[lp*40 + 16 + half*8] = s8z();
    }
    {
        #pragma unroll
        for (int c = 0; c < 8; ++c) {
            int jj = half*64 + c*8;
            short8 t1 = *(const short8*)&T[(size_t)row*256 + jj];
            short8 t2 = *(const short8*)&T[(size_t)col*256 + 128 + jj];
            short8 o;
            #pragma unroll
            for (int i = 0; i < 8; ++i)
                o[i] = (short)f2bf(bf2f((unsigned short)t1[i]) + bf2f((unsigned short)t2[i]));
            *(short8*)&sT[lp*136 + jj] = o;
        }
    }
    __syncthreads();
    const int wave = tid >> 6, lane = tid & 63;
    const int m0 = (wave & 1)*64, n0 = (wave >> 1)*64;
    f32x4 acc[4][4];
    f32x4 z = {0.f, 0.f, 0.f, 0.f};
    #pragma unroll
    for (int mt = 0; mt < 4; ++mt)
        #pragma unroll
        for (int nt = 0; nt < 4; ++nt) acc[mt][nt] = z;
    gemm_tile<1>(sEa + m0*40, 40, WcT, 32, n0, acc, lane);
    const int mr = lane & 15, quad = lane >> 4;
    #pragma unroll
    for (int nt = 0; nt < 4; ++nt) {
        int j = n0 + nt*16 + mr;
        float bia = be1[j];
        float s = 0.f, ssum = 0.f;
        #pragma unroll
        for (int mt = 0; mt < 4; ++mt) {
            int m = m0 + mt*16 + quad*4;
            #pragma unroll
            for (int r = 0; r < 4; ++r) {
                float v = acc[mt][nt][r] + bf2f((unsigned short)sT[(m + r)*136 + j]) + bia;
                hb[(size_t)(p0 + m + r)*H + j] = f2bf(v);
                s += v; ssum += v*v;
            }
        }
        atomicAdd(&sS[j], s);
        atomicAdd(&sSS[j], ssum);
    }
    __syncthreads();
    if (tid < H) { atomicAdd(&gS[tid], sS[tid]); atomicAdd(&gSS[tid], sSS[tid]); }
}

// ---- BN stats -> scale/shift ----
__global__ void k_stats(const float* __restrict__ S, const float* __restrict__ SS,
                        const float* __restrict__ g, const float* __restrict__ b,
                        float invCount, float* __restrict__ scale, float* __restrict__ shift) {
    int j = threadIdx.x;
    float mu = S[j]*invCount;
    float var = SS[j]*invCount - mu*mu;
    float sc = rsqrtf(var + BN_EPS)*g[j];
    scale[j] = sc;
    shift[j] = b[j] - mu*sc;
}

// ---- msg = relu( relu(bn(h1)) @ W2m + b2m ) ; bf16, in place over h1 (sorted order) ----
__launch_bounds__(256)
__global__ void k_edge2(unsigned short* __restrict__ hb,
                        const float* __restrict__ scale, const float* __restrict__ shift,
                        const unsigned short* __restrict__ W2mT, const float* __restrict__ b2m) {
    __shared__ short sA[128*136];
    const int tid = threadIdx.x;
    const size_t e0 = (size_t)blockIdx.x*128;
    {
        const int rowl = tid >> 1, half = (tid & 1)*64;
        const size_t base = (e0 + rowl)*H + half;
        #pragma unroll
        for (int c = 0; c < 8; ++c) {
            int k0 = half + c*8;
            short8 raw = *(const short8*)&hb[base + c*8];
            float4 sc0 = *(const float4*)&scale[k0], sc1 = *(const float4*)&scale[k0 + 4];
            float4 sh0 = *(const float4*)&shift[k0], sh1 = *(const float4*)&shift[k0 + 4];
            short8 o;
            o[0] = (short)f2bf(fmaxf(fmaf(bf2f((unsigned short)raw[0]), sc0.x, sh0.x), 0.f));
            o[1] = (short)f2bf(fmaxf(fmaf(bf2f((unsigned short)raw[1]), sc0.y, sh0.y), 0.f));
            o[2] = (short)f2bf(fmaxf(fmaf(bf2f((unsigned short)raw[2]), sc0.z, sh0.z), 0.f));
            o[3] = (short)f2bf(fmaxf(fmaf(bf2f((unsigned short)raw[3]), sc0.w, sh0.w), 0.f));
            o[4] = (short)f2bf(fmaxf(fmaf(bf2f((unsigned short)raw[4]), sc1.x, sh1.x), 0.f));
            o[5] = (short)f2bf(fmaxf(fmaf(bf2f((unsigned short)raw[5]), sc1.y, sh1.y), 0.f));
            o[6] = (short)f2bf(fmaxf(fmaf(bf2f((unsigned short)raw[6]), sc1.z, sh1.z), 0.f));
            o[7] = (short)f2bf(fmaxf(fmaf(bf2f((unsigned short)raw[7]), sc1.w, sh1.w), 0.f));
            *(short8*)&sA[rowl*136 + k0] = o;
        }
    }
    __syncthreads();
    const int wave = tid >> 6, lane = tid & 63;
    const int m0 = (wave & 1)*64, n0 = (wave >> 1)*64;
    f32x4 acc[4][4];
    f32x4 z = {0.f, 0.f, 0.f, 0.f};
    #pragma unroll
    for (int mt = 0; mt < 4; ++mt)
        #pragma unroll
        for (int nt = 0; nt < 4; ++nt) acc[mt][nt] = z;
    gemm_tile<4>(sA + m0*136, 136, W2mT, 128, n0, acc, lane);
    const int mr = lane & 15, quad = lane >> 4;
    #pragma unroll
    for (int nt = 0; nt < 4; ++nt) {
        int j = n0 + nt*16 + mr;
        float bias = b2m[j];
        #pragma unroll
        for (int mt = 0; mt < 4; ++mt) {
            size_t eb = e0 + m0 + mt*16 + quad*4;
            #pragma unroll
            for (int r = 0; r < 4; ++r)
                hb[(eb + r)*H + j] = f2bf(fmaxf(acc[mt][nt][r] + bias, 0.f));
        }
    }
}

// ---- aggregation: one wave per node, CONTIGUOUS sorted msg rows, f32 acc, bf16 store ----
__launch_bounds__(256)
__global__ void k_agg(const unsigned short* __restrict__ msg, const int* __restrict__ offsets,
                      unsigned short* __restrict__ aggb) {
    const int n = blockIdx.x*4 + (threadIdx.x >> 6);
    const int lane = threadIdx.x & 63;
    const int s0 = offsets[n], t0 = offsets[n + 1];
    float a0 = 0.f, a1 = 0.f;
    for (int p = s0; p < t0; ++p) {
        unsigned int u = *(const unsigned int*)&msg[(size_t)p*H + lane*2];
        a0 += bf2f((unsigned short)(u & 0xFFFFu));
        a1 += bf2f((unsigned short)(u >> 16));
    }
    unsigned int o = (unsigned int)f2bf(a0) | ((unsigned int)f2bf(a1) << 16);
    *(unsigned int*)&aggb[(size_t)n*H + lane*2] = o;
}

// ---- h2 = [x, agg] @ Wn1 + bn1 (f32 store) ; BN stats ----
__launch_bounds__(256)
__global__ void k_node1(const float* __restrict__ x, const unsigned short* __restrict__ aggb,
                        const unsigned short* __restrict__ Wn1T, const float* __restrict__ bn1,
                        float* __restrict__ h2, float* __restrict__ gS, float* __restrict__ gSS) {
    __shared__ short sA[128*200];
    __shared__ float sS[H], sSS[H];
    const int tid = threadIdx.x;
    if (tid < H) { sS[tid] = 0.f; sSS[tid] = 0.f; }
    const int n0b = blockIdx.x*128;
    {
        const int rowl = tid >> 1, half = (tid & 1)*96;
        const int node = n0b + rowl;
        const bool ok = node < NNODES;
        #pragma unroll
        for (int c = 0; c < 12; ++c) {
            int k0 = half + c*8;
            short8 o = s8z();
            if (ok) {
                if (k0 < 64) {
                    float4 a = *(const float4*)&x[node*64 + k0];
                    float4 b = *(const float4*)&x[node*64 + k0 + 4];
                    o[0]=(short)f2bf(a.x); o[1]=(short)f2bf(a.y); o[2]=(short)f2bf(a.z); o[3]=(short)f2bf(a.w);
                    o[4]=(short)f2bf(b.x); o[5]=(short)f2bf(b.y); o[6]=(short)f2bf(b.z); o[7]=(short)f2bf(b.w);
                } else {
                    o = *(const short8*)&aggb[(size_t)node*H + (k0 - 64)];
                }
            }
            *(short8*)&sA[rowl*200 + k0] = o;
        }
    }
    __syncthreads();
    const int wave = tid >> 6, lane = tid & 63;
    const int m0 = (wave & 1)*64, n0 = (wave >> 1)*64;
    f32x4 acc[4][4];
    f32x4 z = {0.f, 0.f, 0.f, 0.f};
    #pragma unroll
    for (int mt = 0; mt < 4; ++mt)
        #pragma unroll
        for (int nt = 0; nt < 4; ++nt) acc[mt][nt] = z;
    gemm_tile<6>(sA + m0*200, 200, Wn1T, 192, n0, acc, lane);
    const int mr = lane & 15, quad = lane >> 4;
    #pragma unroll
    for (int nt = 0; nt < 4; ++nt) {
        int j = n0 + nt*16 + mr;
        float bias = bn1[j];
        float s = 0.f, ssum = 0.f;
        #pragma unroll
        for (int mt = 0; mt < 4; ++mt) {
            int nb = n0b + m0 + mt*16 + quad*4;
            #pragma unroll
            for (int r = 0; r < 4; ++r) {
                int node = nb + r;
                if (node < NNODES) {
                    float v = acc[mt][nt][r] + bias;
                    h2[(size_t)node*H + j] = v;
                    s += v; ssum += v*v;
                }
            }
        }
        atomicAdd(&sS[j], s);
        atomicAdd(&sSS[j], ssum);
    }
    __syncthreads();
    if (tid < H) { atomicAdd(&gS[tid], sS[tid]); atomicAdd(&gSS[tid], sSS[tid]); }
}

// ---- out = relu(bn(h2)) @ Wn2 + bn2 (f32) ----
__launch_bounds__(256)
__global__ void k_node2(const float* __restrict__ h2, const float* __restrict__ scale,
                        const float* __restrict__ shift, const unsigned short* __restrict__ Wn2T,
                        const float* __restrict__ bn2, float* __restrict__ out) {
    __shared__ short sA[128*136];
    const int tid = threadIdx.x;
    const int n0b = blockIdx.x*128;
    {
        const int rowl = tid >> 1, half = (tid & 1)*64;
        const int node = n0b + rowl;
        const bool ok = node < NNODES;
        #pragma unroll
        for (int c = 0; c < 8; ++c) {
            int k0 = half + c*8;
            short8 o = s8z();
            if (ok) {
                float4 a = *(const float4*)&h2[(size_t)node*H + k0];
                float4 b = *(const float4*)&h2[(size_t)node*H + k0 + 4];
                float4 sc0 = *(const float4*)&scale[k0], sc1 = *(const float4*)&scale[k0 + 4];
                float4 sh0 = *(const float4*)&shift[k0], sh1 = *(const float4*)&shift[k0 + 4];
                o[0] = (short)f2bf(fmaxf(fmaf(a.x, sc0.x, sh0.x), 0.f));
                o[1] = (short)f2bf(fmaxf(fmaf(a.y, sc0.y, sh0.y), 0.f));
                o[2] = (short)f2bf(fmaxf(fmaf(a.z, sc0.z, sh0.z), 0.f));
                o[3] = (short)f2bf(fmaxf(fmaf(a.w, sc0.w, sh0.w), 0.f));
                o[4] = (short)f2bf(fmaxf(fmaf(b.x, sc1.x, sh1.x), 0.f));
                o[5] = (short)f2bf(fmaxf(fmaf(b.y, sc1.y, sh1.y), 0.f));
                o[6] = (short)f2bf(fmaxf(fmaf(b.z, sc1.z, sh1.z), 0.f));
                o[7] = (short)f2bf(fmaxf(fmaf(b.w, sc1.w, sh1.w), 0.f));
            }
            *(short8*)&sA[rowl*136 + k0] = o;
        }
    }
    __syncthreads();
    const int wave = tid >> 6, lane = tid & 63;
    const int m0 = (wave & 1)*64, n0 = (wave >> 1)*64;
    f32x4 acc[4][4];
    f32x4 z = {0.f, 0.f, 0.f, 0.f};
    #pragma unroll
    for (int mt = 0; mt < 4; ++mt)
        #pragma unroll
        for (int nt = 0; nt < 4; ++nt) acc[mt][nt] = z;
    gemm_tile<4>(sA + m0*136, 136, Wn2T, 128, n0, acc, lane);
    const int mr = lane & 15, quad = lane >> 4;
    #pragma unroll
    for (int nt = 0; nt < 4; ++nt) {
        int j = n0 + nt*16 + mr;
        float bias = bn2[j];
        #pragma unroll
        for (int mt = 0; mt < 4; ++mt) {
            int nb = n0b + m0 + mt*16 + quad*4;
            #pragma unroll
            for (int r = 0; r < 4; ++r) {
                int node = nb + r;
                if (node < NNODES) out[(size_t)node*H + j] = acc[mt][nt][r] + bias;
            }
        }
    }
}

extern "C" void kernel_launch(void* const* d_in, const int* in_sizes, int n_in,
                              void* d_out, int out_size, void* d_ws, size_t ws_size,
                              hipStream_t stream) {
    (void)in_sizes; (void)n_in; (void)out_size; (void)ws_size;
    const float* x   = (const float*)d_in[0];
    const int*   ei  = (const int*)d_in[1];
    const float* ea  = (const float*)d_in[2];
    const float* We1 = (const float*)d_in[3];
    const float* be1 = (const float*)d_in[4];
    const float* ge  = (const float*)d_in[5];
    const float* bbe = (const float*)d_in[6];
    const float* We2 = (const float*)d_in[7];
    const float* be2 = (const float*)d_in[8];
    const float* Wm  = (const float*)d_in[9];
    const float* bm  = (const float*)d_in[10];
    const float* Wn1 = (const float*)d_in[11];
    const float* bn1 = (const float*)d_in[12];
    const float* gn  = (const float*)d_in[13];
    const float* bbn = (const float*)d_in[14];
    const float* Wn2 = (const float*)d_in[15];
    const float* bn2 = (const float*)d_in[16];
    float* out = (float*)d_out;

    char* ws = (char*)d_ws;
    // [0, 204.8M)       h1 / msg (in place, SORTED order) bf16 [E][128]
    // [204.8M, 217.6M)  agg bf16 [N][128]
    // [217.6M, 243.2M)  T bf16 [N][256]  (h2 f32 [N][128] overlays after k_gather2)
    // [243.2M, ...)     CSR + stats + weight copies
    unsigned short* hb   = (unsigned short*)(ws);
    unsigned short* aggb = (unsigned short*)(ws + 204800000);
    unsigned short* Tbuf = (unsigned short*)(ws + 217600000);
    float*          h2   = (float*)(ws + 217600000);
    int* cnt     = (int*)(ws + 243200000);
    int* offsets = (int*)(ws + 243400192);
    int* cursor  = (int*)(ws + 243600256);
    int* elist   = (int*)(ws + 243800320);
    float* S1     = (float*)(ws + 247000384);
    float* SS1    = S1 + 128;
    float* S2     = S1 + 256;
    float* SS2    = S1 + 384;
    float* scale1 = S1 + 512;
    float* shift1 = S1 + 640;
    float* scale2 = S1 + 768;
    float* shift2 = S1 + 896;
    float* W2m = (float*)(ws + 247004480);
    float* b2m = (float*)(ws + 247070016);
    unsigned short* WabT = (unsigned short*)(ws + 247070592);
    unsigned short* Wn1T = (unsigned short*)(ws + 247103360);
    unsigned short* Wn2T = (unsigned short*)(ws + 247152512);
    unsigned short* W2mT = (unsigned short*)(ws + 247185280);
    unsigned short* WcT  = (unsigned short*)(ws + 247218048);

    hipMemsetAsync(cnt, 0, NNODES*sizeof(int), stream);
    hipMemsetAsync(S1, 0, 512*sizeof(float), stream);

    k_fold<<<H + 1, H, 0, stream>>>(We2, be2, Wm, bm, W2m, b2m);
    k_prep2<<<304, 256, 0, stream>>>(We1, Wn1, Wn2, W2m, WabT, Wn1T, Wn2T, W2mT, WcT);
    k_count<<<NEDGES/256, 256, 0, stream>>>(ei, cnt);
    k_scan<<<1, 1024, 0, stream>>>(cnt, offsets, cursor);
    k_scatter<<<NEDGES/256, 256, 0, stream>>>(ei, cursor, elist);
    k_T<<<dim3(391, 2), 256, 0, stream>>>(x, WabT, Tbuf);
    k_gather2<<<NEDGES/128, 256, 0, stream>>>(Tbuf, ei, elist, ea, WcT, be1, hb, S1, SS1);
    k_stats<<<1, H, 0, stream>>>(S1, SS1, ge, bbe, 1.0f/NEDGES, scale1, shift1);
    k_edge2<<<NEDGES/128, 256, 0, stream>>>(hb, scale1, shift1, W2mT, b2m);
    k_agg<<<NNODES/4, 256, 0, stream>>>(hb, offsets, aggb);
    k_node1<<<391, 256, 0, stream>>>(x, aggb, Wn1T, bn1, h2, S2, SS2);
    k_stats<<<1, H, 0, stream>>>(S2, SS2, gn, bbn, 1.0f/NNODES, scale2, shift2);
    k_node2<<<391, 256, 0, stream>>>(h2, scale2, shift2, Wn2T, bn2, out);
}